// Round 5
// baseline (96.781 us; speedup 1.0000x reference)
//
#include <hip/hip_runtime.h>

#define EPS 1e-7f
#define LOG2E 1.44269504088896340736f

constexpr int BLOCK = 256;   // 4 waves/block, one wave per output j

// Single kernel, one wave per output j:
//   each of the 64 lanes accumulates (num, den) over i = lane, lane+64, ...
//   (coalesced float2/float loads, fully L2-resident), then a 6-step
//   __shfl_xor butterfly reduces across the wave; lane 0 normalizes+stores.
// Math: w = exp(-d2/(2b^2)) = exp2(-((r*px - rx0)^2 + (r*py - ry0)^2)),
//       r = sqrt(log2e/(2 b^2)); the negation folds into v_exp_f32's src
//       modifier. 6 VALU + 1 exp per pair — VALU-issue floor.
__global__ __launch_bounds__(BLOCK) void nw_wave(
    const float2* __restrict__ x,        // M x 2 query points
    const float2* __restrict__ inputs,   // N x 2 data points
    const float*  __restrict__ outputs,  // N
    const float*  __restrict__ bw,       // M
    float*        __restrict__ out,      // M
    int N, int M)
{
    const int lane = threadIdx.x & 63;
    const int j    = blockIdx.x * (BLOCK / 64) + (threadIdx.x >> 6);

    float r = 0.f, rx0 = 0.f, ry0 = 0.f;
    if (j < M) {
        float2 xj = x[j];                // wave-uniform (broadcast load)
        float  b  = bw[j];
        r   = sqrtf(LOG2E / (2.0f * b * b));
        rx0 = r * xj.x;
        ry0 = r * xj.y;
    }

    float num = 0.f, den = 0.f;
    #pragma unroll 8
    for (int i = lane; i < N; i += 64) {
        float2 p = inputs[i];            // coalesced dwordx2 across the wave
        float  o = outputs[i];
        float dx = fmaf(r, p.x, -rx0);
        float dy = fmaf(r, p.y, -ry0);
        float t  = fmaf(dx, dx, dy * dy);
        float w  = __builtin_amdgcn_exp2f(-t);   // neg = free src modifier
        num = fmaf(w, o, num);
        den += w;
    }

    // wave-wide butterfly reduction (64 lanes)
    #pragma unroll
    for (int off = 32; off > 0; off >>= 1) {
        num += __shfl_xor(num, off, 64);
        den += __shfl_xor(den, off, 64);
    }

    if (lane == 0 && j < M) out[j] = num / (den + EPS);
}

extern "C" void kernel_launch(void* const* d_in, const int* in_sizes, int n_in,
                              void* d_out, int out_size, void* d_ws, size_t ws_size,
                              hipStream_t stream) {
    // setup_inputs() dict order: x (M*2), inputs (N*2), outputs (N), bandwidth (M)
    const float2* x       = (const float2*)d_in[0];
    const float2* inputs  = (const float2*)d_in[1];
    const float*  outputs = (const float*) d_in[2];
    const float*  bwv     = (const float*) d_in[3];
    const int N = in_sizes[2];   // outputs element count
    const int M = in_sizes[3];   // bandwidth element count
    float*        out     = (float*)d_out;

    const int waves_per_block = BLOCK / 64;
    dim3 grid((M + waves_per_block - 1) / waves_per_block);   // 2048 blocks @ M=8192
    nw_wave<<<grid, BLOCK, 0, stream>>>(x, inputs, outputs, bwv, out, N, M);
}